// Round 1
// baseline (8328.076 us; speedup 1.0000x reference)
//
#include <hip/hip_runtime.h>
#include <math.h>

#define D 64
#define BR 128          // rows per block
#define BCS 128         // cols per sub-tile
#define NCHUNK 16       // column chunks (grid.y)
#define TLD 132         // padded stride for [k][row] LDS tiles (16B-aligned, breaks pow2 banks)

// Computes, for each row i in its (row-block, column-chunk), partial online-LSE
// over z_j = wlog + (p_j - sqn_col_j)/eps + (x_i . y_j)/eps
// (row constant -sqn_row_i/eps is applied in the merge kernel).
__global__ __launch_bounds__(256, 2)
void softmin_partial(const float* __restrict__ xrow,   // [n_rows][64]
                     const float* __restrict__ ycol,   // [n_cols][64]
                     const float* __restrict__ p,      // [n_cols] or nullptr
                     const float* __restrict__ sqn_col,// [n_cols]
                     const float* __restrict__ eps_list, int eps_idx,
                     float wlog,
                     float* __restrict__ pm, float* __restrict__ ps, // [NCHUNK][n_rows]
                     int n_rows, int n_cols)
{
    __shared__ float xt[D * TLD];
    __shared__ float yt[D * TLD];

    const int t  = threadIdx.x;
    const int tx = t & 15;        // column group 0..15
    const int ty = t >> 4;        // row group 0..15
    const int rb = blockIdx.x;
    const int chunk = blockIdx.y;
    const int cols_per_chunk = n_cols / NCHUNK;   // 512
    const int nsub = cols_per_chunk / BCS;        // 4
    const int row0 = rb * BR;

    const float eps = eps_list[eps_idx];
    const float inv_eps = 1.0f / eps;

    float m[8], s[8];
#pragma unroll
    for (int r = 0; r < 8; ++r) { m[r] = -__builtin_inff(); s[r] = 0.0f; }

    for (int sub = 0; sub < nsub; ++sub) {
        const int col0 = chunk * cols_per_chunk + sub * BCS;
        __syncthreads();   // protect LDS from previous iteration's readers
        // stage 128x64 x-tile and y-tile, transposed to [k][row] layout
#pragma unroll
        for (int i = 0; i < 8; ++i) {
            int f   = t + i * 256;     // 0..2047 float4 index
            int row = f >> 4;          // 0..127
            int kg  = f & 15;          // float4 group along k
            float4 vx = ((const float4*)(xrow + (size_t)(row0 + row) * D))[kg];
            float4 vy = ((const float4*)(ycol + (size_t)(col0 + row) * D))[kg];
            int kb = kg * 4;
            xt[(kb+0)*TLD + row] = vx.x;
            xt[(kb+1)*TLD + row] = vx.y;
            xt[(kb+2)*TLD + row] = vx.z;
            xt[(kb+3)*TLD + row] = vx.w;
            yt[(kb+0)*TLD + row] = vy.x;
            yt[(kb+1)*TLD + row] = vy.y;
            yt[(kb+2)*TLD + row] = vy.z;
            yt[(kb+3)*TLD + row] = vy.w;
        }
        __syncthreads();

        float acc[8][8];
#pragma unroll
        for (int r = 0; r < 8; ++r)
#pragma unroll
            for (int c = 0; c < 8; ++c) acc[r][c] = 0.0f;

#pragma unroll 4
        for (int k = 0; k < D; ++k) {
            float4 xa0 = *(const float4*)&xt[k*TLD + ty*8];
            float4 xa1 = *(const float4*)&xt[k*TLD + ty*8 + 4];
            float4 yb0 = *(const float4*)&yt[k*TLD + tx*8];
            float4 yb1 = *(const float4*)&yt[k*TLD + tx*8 + 4];
            float xr[8] = {xa0.x,xa0.y,xa0.z,xa0.w,xa1.x,xa1.y,xa1.z,xa1.w};
            float yc[8] = {yb0.x,yb0.y,yb0.z,yb0.w,yb1.x,yb1.y,yb1.z,yb1.w};
#pragma unroll
            for (int r = 0; r < 8; ++r)
#pragma unroll
                for (int c = 0; c < 8; ++c)
                    acc[r][c] = fmaf(xr[r], yc[c], acc[r][c]);
        }

        // column constants
        float cj[8];
        {
            int jbase = col0 + tx * 8;
#pragma unroll
            for (int c = 0; c < 8; ++c) {
                int j = jbase + c;
                float pv = p ? p[j] : 0.0f;
                cj[c] = wlog + (pv - sqn_col[j]) * inv_eps;
            }
        }
        // online LSE update per row
#pragma unroll
        for (int r = 0; r < 8; ++r) {
            float z[8];
            float mloc = -__builtin_inff();
#pragma unroll
            for (int c = 0; c < 8; ++c) {
                z[c] = fmaf(acc[r][c], inv_eps, cj[c]);
                mloc = fmaxf(mloc, z[c]);
            }
            float M = fmaxf(m[r], mloc);
            float add = 0.0f;
#pragma unroll
            for (int c = 0; c < 8; ++c) add += __expf(z[c] - M);
            s[r] = s[r] * __expf(m[r] - M) + add;
            m[r] = M;
        }
    }

    // cross-thread (tx) reduction; alias reduction scratch onto xt (done with tiles)
    __syncthreads();
    float* redm = xt;               // [BR][16]
    float* reds = xt + BR * 16;     // [BR][16]
#pragma unroll
    for (int r = 0; r < 8; ++r) {
        int row = ty * 8 + r;
        redm[row * 16 + tx] = m[r];
        reds[row * 16 + tx] = s[r];
    }
    __syncthreads();
    if (t < BR) {
        int row = t;
        float M = -__builtin_inff();
#pragma unroll
        for (int i = 0; i < 16; ++i) M = fmaxf(M, redm[row*16 + i]);
        float S = 0.0f;
#pragma unroll
        for (int i = 0; i < 16; ++i) S += reds[row*16 + i] * __expf(redm[row*16 + i] - M);
        pm[chunk * n_rows + row0 + row] = M;
        ps[chunk * n_rows + row0 + row] = S;
    }
}

__global__ void softmin_merge(const float* __restrict__ pm, const float* __restrict__ ps,
                              const float* __restrict__ sqn_row,
                              const float* __restrict__ eps_list, int eps_idx,
                              const float* __restrict__ oldpot, float* __restrict__ newpot,
                              int n_rows, int mix)
{
    int i = blockIdx.x * blockDim.x + threadIdx.x;
    if (i >= n_rows) return;
    float eps = eps_list[eps_idx];
    float M = -__builtin_inff();
    for (int c = 0; c < NCHUNK; ++c) M = fmaxf(M, pm[c*n_rows + i]);
    float S = 0.0f;
    for (int c = 0; c < NCHUNK; ++c) S += ps[c*n_rows + i] * __expf(pm[c*n_rows + i] - M);
    float val = sqn_row[i] - eps * (M + logf(S));
    newpot[i] = mix ? 0.5f * (oldpot[i] + val) : val;
}

__global__ void sqnorm_kernel(const float* __restrict__ x, float* __restrict__ sqn, int n)
{
    int i = blockIdx.x * blockDim.x + threadIdx.x;
    if (i >= n) return;
    const float4* xp = (const float4*)(x + (size_t)i * D);
    float sum = 0.0f;
#pragma unroll
    for (int k = 0; k < D/4; ++k) {
        float4 v = xp[k];
        sum += v.x*v.x + v.y*v.y + v.z*v.z + v.w*v.w;
    }
    sqn[i] = 0.5f * sum;
}

__global__ void final_reduce(const float* __restrict__ f_ba_f, const float* __restrict__ f_aa_f,
                             const float* __restrict__ g_ab_f, const float* __restrict__ g_bb_f,
                             int n, int mcount, float* __restrict__ out)
{
    __shared__ float red[256];
    float s1 = 0.0f, s2 = 0.0f;
    for (int i = threadIdx.x; i < n; i += 256)      s1 += (f_ba_f[i] - f_aa_f[i]);
    for (int i = threadIdx.x; i < mcount; i += 256) s2 += (g_ab_f[i] - g_bb_f[i]);
    red[threadIdx.x] = s1 / (float)n + s2 / (float)mcount;
    __syncthreads();
    for (int off = 128; off > 0; off >>= 1) {
        if (threadIdx.x < off) red[threadIdx.x] += red[threadIdx.x + off];
        __syncthreads();
    }
    if (threadIdx.x == 0) out[0] = red[0];
}

extern "C" void kernel_launch(void* const* d_in, const int* in_sizes, int n_in,
                              void* d_out, int out_size, void* d_ws, size_t ws_size,
                              hipStream_t stream)
{
    const float* g        = (const float*)d_in[0];
    const float* Y        = (const float*)d_in[1];
    const float* eps_list = (const float*)d_in[2];
    const int N = in_sizes[0] / D;
    const int M = in_sizes[1] / D;
    const int L = in_sizes[2];
    const float a_log = -logf((float)N);
    const float b_log = -logf((float)M);
    const int NM = (N > M) ? N : M;

    float* ws = (float*)d_ws;
    float* sqn_x = ws; ws += N;
    float* sqn_y = ws; ws += M;
    float* fa[2];  fa[0]  = ws; ws += N; fa[1]  = ws; ws += N;
    float* gb[2];  gb[0]  = ws; ws += M; gb[1]  = ws; ws += M;
    float* gab[2]; gab[0] = ws; ws += M; gab[1] = ws; ws += M;
    float* fba[2]; fba[0] = ws; ws += N; fba[1] = ws; ws += N;
    float* f_ba_f = ws; ws += N;
    float* f_aa_f = ws; ws += N;
    float* g_ab_f = ws; ws += M;
    float* g_bb_f = ws; ws += M;
    float* pm = ws; ws += (size_t)NCHUNK * NM;
    float* psb = ws; ws += (size_t)NCHUNK * NM;

    sqnorm_kernel<<<(N + 255) / 256, 256, 0, stream>>>(g, sqn_x, N);
    sqnorm_kernel<<<(M + 255) / 256, 256, 0, stream>>>(Y, sqn_y, M);

    auto softmin = [&](const float* xr, const float* yc, const float* p,
                       const float* sqn_c, const float* sqn_r, int eidx, float wl,
                       const float* oldp, float* newp, int nr, int nc, int mix) {
        dim3 grid(nr / BR, NCHUNK);
        softmin_partial<<<grid, 256, 0, stream>>>(xr, yc, p, sqn_c, eps_list, eidx, wl,
                                                  pm, psb, nr, nc);
        softmin_merge<<<(nr + 255) / 256, 256, 0, stream>>>(pm, psb, sqn_r, eps_list, eidx,
                                                            oldp, newp, nr, mix);
    };

    int cur = 0;
    // initialization at eps_list[0], h = wlog only
    softmin(g, g, nullptr, sqn_x, sqn_x, 0, a_log, nullptr, fa[cur],  N, N, 0); // f_aa
    softmin(Y, Y, nullptr, sqn_y, sqn_y, 0, b_log, nullptr, gb[cur],  M, M, 0); // g_bb
    softmin(Y, g, nullptr, sqn_x, sqn_y, 0, a_log, nullptr, gab[cur], M, N, 0); // g_ab
    softmin(g, Y, nullptr, sqn_y, sqn_x, 0, b_log, nullptr, fba[cur], N, M, 0); // f_ba

    // scan over the full eps schedule; symmetrized averaged updates
    for (int k = 0; k < L; ++k) {
        int nxt = cur ^ 1;
        softmin(g, Y, gab[cur], sqn_y, sqn_x, k, b_log, fba[cur], fba[nxt], N, M, 1); // ft   -> f_ba
        softmin(Y, g, fba[cur], sqn_x, sqn_y, k, a_log, gab[cur], gab[nxt], M, N, 1); // gt   -> g_ab
        softmin(g, g, fa[cur],  sqn_x, sqn_x, k, a_log, fa[cur],  fa[nxt],  N, N, 1); // ftaa -> f_aa
        softmin(Y, Y, gb[cur],  sqn_y, sqn_y, k, b_log, gb[cur],  gb[nxt],  M, M, 1); // gtbb -> g_bb
        cur = nxt;
    }

    // final extrapolation at eps_list[L-1] (no averaging)
    softmin(g, Y, gab[cur], sqn_y, sqn_x, L-1, b_log, nullptr, f_ba_f, N, M, 0);
    softmin(Y, g, fba[cur], sqn_x, sqn_y, L-1, a_log, nullptr, g_ab_f, M, N, 0);
    softmin(g, g, fa[cur],  sqn_x, sqn_x, L-1, a_log, nullptr, f_aa_f, N, N, 0);
    softmin(Y, Y, gb[cur],  sqn_y, sqn_y, L-1, b_log, nullptr, g_bb_f, M, M, 0);

    final_reduce<<<1, 256, 0, stream>>>(f_ba_f, f_aa_f, g_ab_f, g_bb_f, N, M, (float*)d_out);
}

// Round 2
// 3049.258 us; speedup vs baseline: 2.7312x; 2.7312x over previous
//
#include <hip/hip_runtime.h>
#include <math.h>

#define D 64
#define BR 128          // rows per block
#define NCHUNK 16       // column chunks (grid.y)
#define YLD 72          // y-tile row stride in bf16 (64 + 8 pad -> even bank spread)
#define LOG2E 1.4426950408889634f
#define LN2   0.6931471805599453f

typedef __attribute__((ext_vector_type(8))) __bf16 bf16x8;
typedef __attribute__((ext_vector_type(4))) float  floatx4;

static __device__ __forceinline__ unsigned short f2bf_rne(float f) {
    unsigned u = __float_as_uint(f);
    return (unsigned short)((u + 0x7fffu + ((u >> 16) & 1u)) >> 16);
}
static __device__ __forceinline__ float bf2f(unsigned short h) {
    return __uint_as_float(((unsigned)h) << 16);
}

// split fp32 -> (hi, lo) bf16 pair; thread handles 8 elements (16B stores)
__global__ void split_kernel(const float* __restrict__ x,
                             unsigned short* __restrict__ xh,
                             unsigned short* __restrict__ xl, int n_elem8)
{
    int i = blockIdx.x * blockDim.x + threadIdx.x;
    if (i >= n_elem8) return;
    const float4* xp = (const float4*)x;
    float4 v0 = xp[i * 2], v1 = xp[i * 2 + 1];
    float v[8] = {v0.x, v0.y, v0.z, v0.w, v1.x, v1.y, v1.z, v1.w};
    unsigned h[8], l[8];
#pragma unroll
    for (int k = 0; k < 8; ++k) {
        unsigned short hu = f2bf_rne(v[k]);
        float r = v[k] - bf2f(hu);
        unsigned short lu = f2bf_rne(r);
        h[k] = hu; l[k] = lu;
    }
    uint4 ph, pl;
    ph.x = h[0] | (h[1] << 16); ph.y = h[2] | (h[3] << 16);
    ph.z = h[4] | (h[5] << 16); ph.w = h[6] | (h[7] << 16);
    pl.x = l[0] | (l[1] << 16); pl.y = l[2] | (l[3] << 16);
    pl.z = l[4] | (l[5] << 16); pl.w = l[6] | (l[7] << 16);
    ((uint4*)xh)[i] = ph;
    ((uint4*)xl)[i] = pl;
}

__global__ void sqnorm_kernel(const float* __restrict__ x, float* __restrict__ sqn, int n)
{
    int i = blockIdx.x * blockDim.x + threadIdx.x;
    if (i >= n) return;
    const float4* xp = (const float4*)(x + (size_t)i * D);
    float sum = 0.0f;
#pragma unroll
    for (int k = 0; k < D / 4; ++k) {
        float4 v = xp[k];
        sum += v.x * v.x + v.y * v.y + v.z * v.z + v.w * v.w;
    }
    sqn[i] = 0.5f * sum;
}

// MFMA softmin partial: per (row-block, col-chunk), online base-2 LSE over
// z2 = log2e * (wlog + (p_j - sqn_j)/eps + (x_i . y_j)/eps)
// dot via bf16 split: hi*hi + lo*hi + hi*lo (3 MFMAs per k-step)
__global__ __launch_bounds__(256)
void softmin_mfma(const unsigned short* __restrict__ xh, const unsigned short* __restrict__ xl,
                  const unsigned short* __restrict__ yh, const unsigned short* __restrict__ yl,
                  const float* __restrict__ p,           // [n_cols] or nullptr
                  const float* __restrict__ sqn_col,     // [n_cols]
                  const float* __restrict__ eps_list, int eps_idx, float wlog,
                  float* __restrict__ pm, float* __restrict__ ps,  // [NCHUNK][n_rows]
                  int n_rows, int n_cols)
{
    __shared__ __bf16 yth[128 * YLD];
    __shared__ __bf16 ytl[128 * YLD];
    __shared__ float  cc2s[128];

    const int t    = threadIdx.x;
    const int lane = t & 63;
    const int w    = t >> 6;        // wave 0..3, owns 32 rows
    const int lx   = lane & 15;     // col-in-tile / A-row selector
    const int q    = lane >> 4;     // quad 0..3
    const int rb = blockIdx.x, chunk = blockIdx.y;
    const int cols_per_chunk = n_cols / NCHUNK;   // 512
    const int nsub = cols_per_chunk / 128;        // 4
    const int row0 = rb * BR;

    const float eps     = eps_list[eps_idx];
    const float inv_eps = 1.0f / eps;
    const float scale2  = inv_eps * LOG2E;

    // A fragments: rows r0..r0+31, loaded once, reused for every column
    // frag layout: lane holds row (base + lx), k = ks*32 + q*8 .. +7 (16B contiguous)
    bf16x8 ah[2][2], al[2][2];
    {
        const int r0 = row0 + w * 32;
#pragma unroll
        for (int rt = 0; rt < 2; ++rt)
#pragma unroll
            for (int ks = 0; ks < 2; ++ks) {
                size_t off = (size_t)(r0 + rt * 16 + lx) * D + ks * 32 + q * 8;
                ah[rt][ks] = *(const bf16x8*)(xh + off);
                al[rt][ks] = *(const bf16x8*)(xl + off);
            }
    }

    float m[8], s[8];
#pragma unroll
    for (int i = 0; i < 8; ++i) { m[i] = -__builtin_inff(); s[i] = 0.0f; }

    for (int sub = 0; sub < nsub; ++sub) {
        const int col0 = chunk * cols_per_chunk + sub * 128;
        __syncthreads();   // protect LDS from previous iteration's readers
        {
            const uint4* gh = (const uint4*)(yh + (size_t)col0 * D);  // [128 rows][8 x 16B]
            const uint4* gl = (const uint4*)(yl + (size_t)col0 * D);
#pragma unroll
            for (int i = 0; i < 4; ++i) {
                int c = t + i * 256;           // 0..1023
                int row = c >> 3, part = c & 7;
                uint4 vh = gh[c];
                uint4 vl = gl[c];
                *(uint4*)(&yth[row * YLD + part * 8]) = vh;
                *(uint4*)(&ytl[row * YLD + part * 8]) = vl;
            }
            if (t < 128) {
                int col = col0 + t;
                float pv = p ? p[col] : 0.0f;
                cc2s[t] = (wlog + (pv - sqn_col[col]) * inv_eps) * LOG2E;
            }
        }
        __syncthreads();

        floatx4 acc[8][2];
#pragma unroll
        for (int ct = 0; ct < 8; ++ct)
#pragma unroll
            for (int rt = 0; rt < 2; ++rt) acc[ct][rt] = (floatx4){0.f, 0.f, 0.f, 0.f};

#pragma unroll
        for (int ct = 0; ct < 8; ++ct) {
            const int cl = ct * 16 + lx;
            bf16x8 bh0 = *(const bf16x8*)&yth[cl * YLD + q * 8];
            bf16x8 bh1 = *(const bf16x8*)&yth[cl * YLD + 32 + q * 8];
            bf16x8 bl0 = *(const bf16x8*)&ytl[cl * YLD + q * 8];
            bf16x8 bl1 = *(const bf16x8*)&ytl[cl * YLD + 32 + q * 8];
#pragma unroll
            for (int rt = 0; rt < 2; ++rt) {
                floatx4 a = acc[ct][rt];
                a = __builtin_amdgcn_mfma_f32_16x16x32_bf16(ah[rt][0], bh0, a, 0, 0, 0);
                a = __builtin_amdgcn_mfma_f32_16x16x32_bf16(ah[rt][1], bh1, a, 0, 0, 0);
                a = __builtin_amdgcn_mfma_f32_16x16x32_bf16(al[rt][0], bh0, a, 0, 0, 0);
                a = __builtin_amdgcn_mfma_f32_16x16x32_bf16(al[rt][1], bh1, a, 0, 0, 0);
                a = __builtin_amdgcn_mfma_f32_16x16x32_bf16(ah[rt][0], bl0, a, 0, 0, 0);
                a = __builtin_amdgcn_mfma_f32_16x16x32_bf16(ah[rt][1], bl1, a, 0, 0, 0);
                acc[ct][rt] = a;
            }
        }

        float cc[8];
#pragma unroll
        for (int ct = 0; ct < 8; ++ct) cc[ct] = cc2s[ct * 16 + lx];

        // epilogue: batched online-LSE update, one rescale per row per 128 cols
        // C layout: value acc[ct][rt][r] is row (rt*16 + q*4 + r), col (ct*16 + lx)
#pragma unroll
        for (int rt = 0; rt < 2; ++rt)
#pragma unroll
            for (int r = 0; r < 4; ++r) {
                const int idx = rt * 4 + r;
                float z[8];
                float zm = -__builtin_inff();
#pragma unroll
                for (int ct = 0; ct < 8; ++ct) {
                    z[ct] = fmaf(acc[ct][rt][r], scale2, cc[ct]);
                    zm = fmaxf(zm, z[ct]);
                }
                const float M = fmaxf(m[idx], zm);
                float add = 0.0f;
#pragma unroll
                for (int ct = 0; ct < 8; ++ct) add += exp2f(z[ct] - M);
                s[idx] = s[idx] * exp2f(m[idx] - M) + add;
                m[idx] = M;
            }
    }

    // reduce (m,s) across the 16 lanes sharing the same rows (same q within wave)
#pragma unroll
    for (int idx = 0; idx < 8; ++idx) {
        float mm = m[idx], ss = s[idx];
#pragma unroll
        for (int d = 1; d < 16; d <<= 1) {
            float mo = __shfl_xor(mm, d, 64);
            float so = __shfl_xor(ss, d, 64);
            float M = fmaxf(mm, mo);
            ss = ss * exp2f(mm - M) + so * exp2f(mo - M);
            mm = M;
        }
        m[idx] = mm; s[idx] = ss;
    }
    if (lx == 0) {
#pragma unroll
        for (int idx = 0; idx < 8; ++idx) {
            const int rt = idx >> 2, r = idx & 3;
            const int row = row0 + w * 32 + rt * 16 + q * 4 + r;
            pm[chunk * n_rows + row] = m[idx];
            ps[chunk * n_rows + row] = s[idx];
        }
    }
}

__global__ void softmin_merge(const float* __restrict__ pm, const float* __restrict__ ps,
                              const float* __restrict__ sqn_row,
                              const float* __restrict__ eps_list, int eps_idx,
                              const float* __restrict__ oldpot, float* __restrict__ newpot,
                              int n_rows, int mix)
{
    int i = blockIdx.x * blockDim.x + threadIdx.x;
    if (i >= n_rows) return;
    float eps = eps_list[eps_idx];
    float M = -__builtin_inff();
    for (int c = 0; c < NCHUNK; ++c) M = fmaxf(M, pm[c * n_rows + i]);
    float S = 0.0f;
    for (int c = 0; c < NCHUNK; ++c) S += ps[c * n_rows + i] * exp2f(pm[c * n_rows + i] - M);
    float val = sqn_row[i] - eps * LN2 * (M + log2f(S));
    newpot[i] = mix ? 0.5f * (oldpot[i] + val) : val;
}

__global__ void final_reduce(const float* __restrict__ f_ba_f, const float* __restrict__ f_aa_f,
                             const float* __restrict__ g_ab_f, const float* __restrict__ g_bb_f,
                             int n, int mcount, float* __restrict__ out)
{
    __shared__ float red[256];
    float s1 = 0.0f, s2 = 0.0f;
    for (int i = threadIdx.x; i < n; i += 256)      s1 += (f_ba_f[i] - f_aa_f[i]);
    for (int i = threadIdx.x; i < mcount; i += 256) s2 += (g_ab_f[i] - g_bb_f[i]);
    red[threadIdx.x] = s1 / (float)n + s2 / (float)mcount;
    __syncthreads();
    for (int off = 128; off > 0; off >>= 1) {
        if (threadIdx.x < off) red[threadIdx.x] += red[threadIdx.x + off];
        __syncthreads();
    }
    if (threadIdx.x == 0) out[0] = red[0];
}

extern "C" void kernel_launch(void* const* d_in, const int* in_sizes, int n_in,
                              void* d_out, int out_size, void* d_ws, size_t ws_size,
                              hipStream_t stream)
{
    const float* g        = (const float*)d_in[0];
    const float* Y        = (const float*)d_in[1];
    const float* eps_list = (const float*)d_in[2];
    const int N = in_sizes[0] / D;
    const int M = in_sizes[1] / D;
    const int L = in_sizes[2];
    const float a_log = -logf((float)N);
    const float b_log = -logf((float)M);
    const int NM = (N > M) ? N : M;

    // bf16 split buffers first (16B-aligned carve)
    unsigned short* us = (unsigned short*)d_ws;
    unsigned short* gxh = us; us += (size_t)N * D;
    unsigned short* gxl = us; us += (size_t)N * D;
    unsigned short* gyh = us; us += (size_t)M * D;
    unsigned short* gyl = us; us += (size_t)M * D;

    float* ws = (float*)us;
    float* sqn_x = ws; ws += N;
    float* sqn_y = ws; ws += M;
    float* fa[2];  fa[0]  = ws; ws += N; fa[1]  = ws; ws += N;
    float* gb[2];  gb[0]  = ws; ws += M; gb[1]  = ws; ws += M;
    float* gab[2]; gab[0] = ws; ws += M; gab[1] = ws; ws += M;
    float* fba[2]; fba[0] = ws; ws += N; fba[1] = ws; ws += N;
    float* f_ba_f = ws; ws += N;
    float* f_aa_f = ws; ws += N;
    float* g_ab_f = ws; ws += M;
    float* g_bb_f = ws; ws += M;
    float* pm = ws; ws += (size_t)NCHUNK * NM;
    float* psb = ws; ws += (size_t)NCHUNK * NM;

    sqnorm_kernel<<<(N + 255) / 256, 256, 0, stream>>>(g, sqn_x, N);
    sqnorm_kernel<<<(M + 255) / 256, 256, 0, stream>>>(Y, sqn_y, M);
    split_kernel<<<(N * D / 8 + 255) / 256, 256, 0, stream>>>(g, gxh, gxl, N * D / 8);
    split_kernel<<<(M * D / 8 + 255) / 256, 256, 0, stream>>>(Y, gyh, gyl, M * D / 8);

    auto softmin = [&](const unsigned short* rxh, const unsigned short* rxl,
                       const unsigned short* cyh, const unsigned short* cyl,
                       const float* p, const float* sqn_c, const float* sqn_r,
                       int eidx, float wl, const float* oldp, float* newp,
                       int nr, int nc, int mix) {
        dim3 grid(nr / BR, NCHUNK);
        softmin_mfma<<<grid, 256, 0, stream>>>(rxh, rxl, cyh, cyl, p, sqn_c, eps_list,
                                               eidx, wl, pm, psb, nr, nc);
        softmin_merge<<<(nr + 255) / 256, 256, 0, stream>>>(pm, psb, sqn_r, eps_list, eidx,
                                                            oldp, newp, nr, mix);
    };

    int cur = 0;
    // initialization at eps_list[0], h = wlog only
    softmin(gxh, gxl, gxh, gxl, nullptr, sqn_x, sqn_x, 0, a_log, nullptr, fa[cur],  N, N, 0);
    softmin(gyh, gyl, gyh, gyl, nullptr, sqn_y, sqn_y, 0, b_log, nullptr, gb[cur],  M, M, 0);
    softmin(gyh, gyl, gxh, gxl, nullptr, sqn_x, sqn_y, 0, a_log, nullptr, gab[cur], M, N, 0);
    softmin(gxh, gxl, gyh, gyl, nullptr, sqn_y, sqn_x, 0, b_log, nullptr, fba[cur], N, M, 0);

    // scan over the eps schedule; symmetrized averaged updates
    for (int k = 0; k < L; ++k) {
        int nxt = cur ^ 1;
        softmin(gxh, gxl, gyh, gyl, gab[cur], sqn_y, sqn_x, k, b_log, fba[cur], fba[nxt], N, M, 1);
        softmin(gyh, gyl, gxh, gxl, fba[cur], sqn_x, sqn_y, k, a_log, gab[cur], gab[nxt], M, N, 1);
        softmin(gxh, gxl, gxh, gxl, fa[cur],  sqn_x, sqn_x, k, a_log, fa[cur],  fa[nxt],  N, N, 1);
        softmin(gyh, gyl, gyh, gyl, gb[cur],  sqn_y, sqn_y, k, b_log, gb[cur],  gb[nxt],  M, M, 1);
        cur = nxt;
    }

    // final extrapolation at eps_list[L-1] (no averaging)
    softmin(gxh, gxl, gyh, gyl, gab[cur], sqn_y, sqn_x, L - 1, b_log, nullptr, f_ba_f, N, M, 0);
    softmin(gyh, gyl, gxh, gxl, fba[cur], sqn_x, sqn_y, L - 1, a_log, nullptr, g_ab_f, M, N, 0);
    softmin(gxh, gxl, gxh, gxl, fa[cur],  sqn_x, sqn_x, L - 1, a_log, nullptr, f_aa_f, N, N, 0);
    softmin(gyh, gyl, gyh, gyl, gb[cur],  sqn_y, sqn_y, L - 1, b_log, nullptr, g_bb_f, M, M, 0);

    final_reduce<<<1, 256, 0, stream>>>(f_ba_f, f_aa_f, g_ab_f, g_bb_f, N, M, (float*)d_out);
}

// Round 3
// 2204.397 us; speedup vs baseline: 3.7779x; 1.3833x over previous
//
#include <hip/hip_runtime.h>
#include <math.h>

#define D 64
#define BR 128          // rows per block
#define NCHUNK 16       // column chunks (grid.y)
#define YLD 72          // y-tile row stride in bf16 (64 + 8 pad -> even bank spread)
#define LOG2E 1.4426950408889634f
#define LN2   0.6931471805599453f

typedef __attribute__((ext_vector_type(8))) __bf16 bf16x8;
typedef __attribute__((ext_vector_type(4))) float  floatx4;
typedef __attribute__((ext_vector_type(2))) float  floatx2;

static __device__ __forceinline__ float exp2fast(float x) {
#if __has_builtin(__builtin_amdgcn_exp2f)
    return __builtin_amdgcn_exp2f(x);   // raw v_exp_f32, 1 ulp
#else
    return exp2f(x);
#endif
}
static __device__ __forceinline__ float log2fast(float x) {
#if __has_builtin(__builtin_amdgcn_logf)
    return __builtin_amdgcn_logf(x);    // raw v_log_f32 (log2)
#else
    return log2f(x);
#endif
}

static __device__ __forceinline__ unsigned short f2bf_rne(float f) {
    unsigned u = __float_as_uint(f);
    return (unsigned short)((u + 0x7fffu + ((u >> 16) & 1u)) >> 16);
}
static __device__ __forceinline__ float bf2f(unsigned short h) {
    return __uint_as_float(((unsigned)h) << 16);
}

// split fp32 -> (hi, lo) bf16 pair; thread handles 8 elements (16B stores)
__global__ void split_kernel(const float* __restrict__ x,
                             unsigned short* __restrict__ xh,
                             unsigned short* __restrict__ xl, int n_elem8)
{
    int i = blockIdx.x * blockDim.x + threadIdx.x;
    if (i >= n_elem8) return;
    const float4* xp = (const float4*)x;
    float4 v0 = xp[i * 2], v1 = xp[i * 2 + 1];
    float v[8] = {v0.x, v0.y, v0.z, v0.w, v1.x, v1.y, v1.z, v1.w};
    unsigned h[8], l[8];
#pragma unroll
    for (int k = 0; k < 8; ++k) {
        unsigned short hu = f2bf_rne(v[k]);
        float r = v[k] - bf2f(hu);
        unsigned short lu = f2bf_rne(r);
        h[k] = hu; l[k] = lu;
    }
    uint4 ph, pl;
    ph.x = h[0] | (h[1] << 16); ph.y = h[2] | (h[3] << 16);
    ph.z = h[4] | (h[5] << 16); ph.w = h[6] | (h[7] << 16);
    pl.x = l[0] | (l[1] << 16); pl.y = l[2] | (l[3] << 16);
    pl.z = l[4] | (l[5] << 16); pl.w = l[6] | (l[7] << 16);
    ((uint4*)xh)[i] = ph;
    ((uint4*)xl)[i] = pl;
}

__global__ void sqnorm_kernel(const float* __restrict__ x, float* __restrict__ sqn, int n)
{
    int i = blockIdx.x * blockDim.x + threadIdx.x;
    if (i >= n) return;
    const float4* xp = (const float4*)(x + (size_t)i * D);
    float sum = 0.0f;
#pragma unroll
    for (int k = 0; k < D / 4; ++k) {
        float4 v = xp[k];
        sum += v.x * v.x + v.y * v.y + v.z * v.z + v.w * v.w;
    }
    sqn[i] = 0.5f * sum;
}

// MFMA softmin partial: per (row-block, col-chunk), online base-2 LSE over
// z2 = log2e * (wlog + (p_j - sqn_j)/eps + (x_i . y_j)/eps)
// dot via bf16 split: hi*hi + lo*hi + hi*lo (3 MFMAs per k-step)
__global__ __launch_bounds__(256)
void softmin_mfma(const unsigned short* __restrict__ xh, const unsigned short* __restrict__ xl,
                  const unsigned short* __restrict__ yh, const unsigned short* __restrict__ yl,
                  const float* __restrict__ p,           // [n_cols] or nullptr
                  const float* __restrict__ sqn_col,     // [n_cols]
                  const float* __restrict__ eps_list, int eps_idx, float wlog,
                  float* __restrict__ pm, float* __restrict__ ps,  // [NCHUNK][n_rows]
                  int n_rows, int n_cols)
{
    __shared__ __bf16 yth[128 * YLD];
    __shared__ __bf16 ytl[128 * YLD];
    __shared__ float  cc2s[128];

    const int t    = threadIdx.x;
    const int lane = t & 63;
    const int w    = t >> 6;        // wave 0..3, owns 32 rows
    const int lx   = lane & 15;     // col-in-tile / A-row selector
    const int q    = lane >> 4;     // quad 0..3
    const int rb = blockIdx.x, chunk = blockIdx.y;
    const int cols_per_chunk = n_cols / NCHUNK;   // 512
    const int nsub = cols_per_chunk / 128;        // 4
    const int row0 = rb * BR;

    const float eps     = eps_list[eps_idx];
    const float inv_eps = 1.0f / eps;
    const float scale2  = inv_eps * LOG2E;
    const floatx2 s2v   = (floatx2){scale2, scale2};

    // A fragments: rows r0..r0+31, loaded once, reused for every column
    bf16x8 ah[2][2], al[2][2];
    {
        const int r0 = row0 + w * 32;
#pragma unroll
        for (int rt = 0; rt < 2; ++rt)
#pragma unroll
            for (int ks = 0; ks < 2; ++ks) {
                size_t off = (size_t)(r0 + rt * 16 + lx) * D + ks * 32 + q * 8;
                ah[rt][ks] = *(const bf16x8*)(xh + off);
                al[rt][ks] = *(const bf16x8*)(xl + off);
            }
    }

    float m[8], s[8];
#pragma unroll
    for (int i = 0; i < 8; ++i) { m[i] = -__builtin_inff(); s[i] = 0.0f; }

    for (int sub = 0; sub < nsub; ++sub) {
        const int col0 = chunk * cols_per_chunk + sub * 128;
        __syncthreads();   // protect LDS from previous iteration's readers
        {
            const uint4* gh = (const uint4*)(yh + (size_t)col0 * D);  // [128 rows][8 x 16B]
            const uint4* gl = (const uint4*)(yl + (size_t)col0 * D);
#pragma unroll
            for (int i = 0; i < 4; ++i) {
                int c = t + i * 256;           // 0..1023
                int row = c >> 3, part = c & 7;
                uint4 vh = gh[c];
                uint4 vl = gl[c];
                *(uint4*)(&yth[row * YLD + part * 8]) = vh;
                *(uint4*)(&ytl[row * YLD + part * 8]) = vl;
            }
            if (t < 128) {
                int col = col0 + t;
                float pv = p ? p[col] : 0.0f;
                cc2s[t] = (wlog + (pv - sqn_col[col]) * inv_eps) * LOG2E;
            }
        }
        __syncthreads();

        floatx4 acc[8][2];
#pragma unroll
        for (int ct = 0; ct < 8; ++ct)
#pragma unroll
            for (int rt = 0; rt < 2; ++rt) acc[ct][rt] = (floatx4){0.f, 0.f, 0.f, 0.f};

#pragma unroll
        for (int ct = 0; ct < 8; ++ct) {
            const int cl = ct * 16 + lx;
            bf16x8 bh0 = *(const bf16x8*)&yth[cl * YLD + q * 8];
            bf16x8 bh1 = *(const bf16x8*)&yth[cl * YLD + 32 + q * 8];
            bf16x8 bl0 = *(const bf16x8*)&ytl[cl * YLD + q * 8];
            bf16x8 bl1 = *(const bf16x8*)&ytl[cl * YLD + 32 + q * 8];
#pragma unroll
            for (int rt = 0; rt < 2; ++rt) {
                floatx4 a = acc[ct][rt];
                a = __builtin_amdgcn_mfma_f32_16x16x32_bf16(ah[rt][0], bh0, a, 0, 0, 0);
                a = __builtin_amdgcn_mfma_f32_16x16x32_bf16(ah[rt][1], bh1, a, 0, 0, 0);
                a = __builtin_amdgcn_mfma_f32_16x16x32_bf16(al[rt][0], bh0, a, 0, 0, 0);
                a = __builtin_amdgcn_mfma_f32_16x16x32_bf16(al[rt][1], bh1, a, 0, 0, 0);
                a = __builtin_amdgcn_mfma_f32_16x16x32_bf16(ah[rt][0], bl0, a, 0, 0, 0);
                a = __builtin_amdgcn_mfma_f32_16x16x32_bf16(ah[rt][1], bl1, a, 0, 0, 0);
                acc[ct][rt] = a;
            }
        }

        // column constants as packed pairs
        floatx2 ccv[4];
#pragma unroll
        for (int cp = 0; cp < 4; ++cp)
            ccv[cp] = (floatx2){cc2s[(cp * 2) * 16 + lx], cc2s[(cp * 2 + 1) * 16 + lx]};

        // epilogue: batched online-LSE update, packed fp32 (v_pk_*), native v_exp
        // C layout: acc[ct][rt][r] is row (rt*16 + q*4 + r), col (ct*16 + lx)
#pragma unroll
        for (int rt = 0; rt < 2; ++rt)
#pragma unroll
            for (int r = 0; r < 4; ++r) {
                const int idx = rt * 4 + r;
                floatx2 zv[4];
#pragma unroll
                for (int cp = 0; cp < 4; ++cp) {
                    floatx2 av = (floatx2){acc[cp * 2][rt][r], acc[cp * 2 + 1][rt][r]};
                    zv[cp] = __builtin_elementwise_fma(av, s2v, ccv[cp]);
                }
                floatx2 zm2 = __builtin_elementwise_max(
                    __builtin_elementwise_max(zv[0], zv[1]),
                    __builtin_elementwise_max(zv[2], zv[3]));
                const float M = fmaxf(m[idx], fmaxf(zm2.x, zm2.y));
                const floatx2 Mv = (floatx2){M, M};
                floatx2 sv = (floatx2){0.f, 0.f};
#pragma unroll
                for (int cp = 0; cp < 4; ++cp) {
                    floatx2 d = zv[cp] - Mv;
                    sv += (floatx2){exp2fast(d.x), exp2fast(d.y)};
                }
                s[idx] = fmaf(s[idx], exp2fast(m[idx] - M), sv.x + sv.y);
                m[idx] = M;
            }
    }

    // reduce (m,s) across the 16 lanes sharing the same rows
#pragma unroll
    for (int idx = 0; idx < 8; ++idx) {
        float mm = m[idx], ss = s[idx];
#pragma unroll
        for (int d = 1; d < 16; d <<= 1) {
            float mo = __shfl_xor(mm, d, 64);
            float so = __shfl_xor(ss, d, 64);
            float M = fmaxf(mm, mo);
            ss = ss * exp2fast(mm - M) + so * exp2fast(mo - M);
            mm = M;
        }
        m[idx] = mm; s[idx] = ss;
    }
    if (lx == 0) {
#pragma unroll
        for (int idx = 0; idx < 8; ++idx) {
            const int rt = idx >> 2, r = idx & 3;
            const int row = row0 + w * 32 + rt * 16 + q * 4 + r;
            pm[chunk * n_rows + row] = m[idx];
            ps[chunk * n_rows + row] = s[idx];
        }
    }
}

__global__ void softmin_merge(const float* __restrict__ pm, const float* __restrict__ ps,
                              const float* __restrict__ sqn_row,
                              const float* __restrict__ eps_list, int eps_idx,
                              const float* __restrict__ oldpot, float* __restrict__ newpot,
                              int n_rows, int mix)
{
    int i = blockIdx.x * blockDim.x + threadIdx.x;
    if (i >= n_rows) return;
    float eps = eps_list[eps_idx];
    float M = -__builtin_inff();
    for (int c = 0; c < NCHUNK; ++c) M = fmaxf(M, pm[c * n_rows + i]);
    float S = 0.0f;
    for (int c = 0; c < NCHUNK; ++c) S += ps[c * n_rows + i] * exp2fast(pm[c * n_rows + i] - M);
    float val = sqn_row[i] - eps * LN2 * (M + log2fast(S));
    newpot[i] = mix ? 0.5f * (oldpot[i] + val) : val;
}

__global__ void final_reduce(const float* __restrict__ f_ba_f, const float* __restrict__ f_aa_f,
                             const float* __restrict__ g_ab_f, const float* __restrict__ g_bb_f,
                             int n, int mcount, float* __restrict__ out)
{
    __shared__ float red[256];
    float s1 = 0.0f, s2 = 0.0f;
    for (int i = threadIdx.x; i < n; i += 256)      s1 += (f_ba_f[i] - f_aa_f[i]);
    for (int i = threadIdx.x; i < mcount; i += 256) s2 += (g_ab_f[i] - g_bb_f[i]);
    red[threadIdx.x] = s1 / (float)n + s2 / (float)mcount;
    __syncthreads();
    for (int off = 128; off > 0; off >>= 1) {
        if (threadIdx.x < off) red[threadIdx.x] += red[threadIdx.x + off];
        __syncthreads();
    }
    if (threadIdx.x == 0) out[0] = red[0];
}

extern "C" void kernel_launch(void* const* d_in, const int* in_sizes, int n_in,
                              void* d_out, int out_size, void* d_ws, size_t ws_size,
                              hipStream_t stream)
{
    const float* g        = (const float*)d_in[0];
    const float* Y        = (const float*)d_in[1];
    const float* eps_list = (const float*)d_in[2];
    const int N = in_sizes[0] / D;
    const int M = in_sizes[1] / D;
    const int L = in_sizes[2];
    const float a_log = -logf((float)N);
    const float b_log = -logf((float)M);
    const int NM = (N > M) ? N : M;

    // bf16 split buffers first (16B-aligned carve)
    unsigned short* us = (unsigned short*)d_ws;
    unsigned short* gxh = us; us += (size_t)N * D;
    unsigned short* gxl = us; us += (size_t)N * D;
    unsigned short* gyh = us; us += (size_t)M * D;
    unsigned short* gyl = us; us += (size_t)M * D;

    float* ws = (float*)us;
    float* sqn_x = ws; ws += N;
    float* sqn_y = ws; ws += M;
    float* fa[2];  fa[0]  = ws; ws += N; fa[1]  = ws; ws += N;
    float* gb[2];  gb[0]  = ws; ws += M; gb[1]  = ws; ws += M;
    float* gab[2]; gab[0] = ws; ws += M; gab[1] = ws; ws += M;
    float* fba[2]; fba[0] = ws; ws += N; fba[1] = ws; ws += N;
    float* f_ba_f = ws; ws += N;
    float* f_aa_f = ws; ws += N;
    float* g_ab_f = ws; ws += M;
    float* g_bb_f = ws; ws += M;
    float* pm = ws; ws += (size_t)NCHUNK * NM;
    float* psb = ws; ws += (size_t)NCHUNK * NM;

    sqnorm_kernel<<<(N + 255) / 256, 256, 0, stream>>>(g, sqn_x, N);
    sqnorm_kernel<<<(M + 255) / 256, 256, 0, stream>>>(Y, sqn_y, M);
    split_kernel<<<(N * D / 8 + 255) / 256, 256, 0, stream>>>(g, gxh, gxl, N * D / 8);
    split_kernel<<<(M * D / 8 + 255) / 256, 256, 0, stream>>>(Y, gyh, gyl, M * D / 8);

    auto softmin = [&](const unsigned short* rxh, const unsigned short* rxl,
                       const unsigned short* cyh, const unsigned short* cyl,
                       const float* p, const float* sqn_c, const float* sqn_r,
                       int eidx, float wl, const float* oldp, float* newp,
                       int nr, int nc, int mix) {
        dim3 grid(nr / BR, NCHUNK);
        softmin_mfma<<<grid, 256, 0, stream>>>(rxh, rxl, cyh, cyl, p, sqn_c, eps_list,
                                               eidx, wl, pm, psb, nr, nc);
        softmin_merge<<<(nr + 255) / 256, 256, 0, stream>>>(pm, psb, sqn_r, eps_list, eidx,
                                                            oldp, newp, nr, mix);
    };

    int cur = 0;
    // initialization at eps_list[0], h = wlog only
    softmin(gxh, gxl, gxh, gxl, nullptr, sqn_x, sqn_x, 0, a_log, nullptr, fa[cur],  N, N, 0);
    softmin(gyh, gyl, gyh, gyl, nullptr, sqn_y, sqn_y, 0, b_log, nullptr, gb[cur],  M, M, 0);
    softmin(gyh, gyl, gxh, gxl, nullptr, sqn_x, sqn_y, 0, a_log, nullptr, gab[cur], M, N, 0);
    softmin(gxh, gxl, gyh, gyl, nullptr, sqn_y, sqn_x, 0, b_log, nullptr, fba[cur], N, M, 0);

    // scan over the eps schedule; symmetrized averaged updates
    for (int k = 0; k < L; ++k) {
        int nxt = cur ^ 1;
        softmin(gxh, gxl, gyh, gyl, gab[cur], sqn_y, sqn_x, k, b_log, fba[cur], fba[nxt], N, M, 1);
        softmin(gyh, gyl, gxh, gxl, fba[cur], sqn_x, sqn_y, k, a_log, gab[cur], gab[nxt], M, N, 1);
        softmin(gxh, gxl, gxh, gxl, fa[cur],  sqn_x, sqn_x, k, a_log, fa[cur],  fa[nxt],  N, N, 1);
        softmin(gyh, gyl, gyh, gyl, gb[cur],  sqn_y, sqn_y, k, b_log, gb[cur],  gb[nxt],  M, M, 1);
        cur = nxt;
    }

    // final extrapolation at eps_list[L-1] (no averaging)
    softmin(gxh, gxl, gyh, gyl, gab[cur], sqn_y, sqn_x, L - 1, b_log, nullptr, f_ba_f, N, M, 0);
    softmin(gyh, gyl, gxh, gxl, fba[cur], sqn_x, sqn_y, L - 1, a_log, nullptr, g_ab_f, M, N, 0);
    softmin(gxh, gxl, gxh, gxl, fa[cur],  sqn_x, sqn_x, L - 1, a_log, nullptr, f_aa_f, N, N, 0);
    softmin(gyh, gyl, gyh, gyl, gb[cur],  sqn_y, sqn_y, L - 1, b_log, nullptr, g_bb_f, M, M, 0);

    final_reduce<<<1, 256, 0, stream>>>(f_ba_f, f_aa_f, g_ab_f, g_bb_f, N, M, (float*)d_out);
}

// Round 4
// 1713.296 us; speedup vs baseline: 4.8609x; 1.2866x over previous
//
#include <hip/hip_runtime.h>
#include <math.h>

#define D 64
#define BR 128          // rows per block
#define NCHUNK 16       // column chunks (grid.y)
#define YLD 72          // y-tile row stride in bf16 (64 + 8 pad -> even bank spread)
#define LOG2E 1.4426950408889634f
#define LN2   0.6931471805599453f

typedef __attribute__((ext_vector_type(8))) __bf16 bf16x8;
typedef __attribute__((ext_vector_type(4))) float  floatx4;
typedef __attribute__((ext_vector_type(2))) float  floatx2;

static __device__ __forceinline__ float exp2fast(float x) {
#if __has_builtin(__builtin_amdgcn_exp2f)
    return __builtin_amdgcn_exp2f(x);   // raw v_exp_f32, 1 ulp
#else
    return exp2f(x);
#endif
}
static __device__ __forceinline__ float log2fast(float x) {
#if __has_builtin(__builtin_amdgcn_logf)
    return __builtin_amdgcn_logf(x);    // raw v_log_f32 (log2)
#else
    return log2f(x);
#endif
}

static __device__ __forceinline__ unsigned short f2bf_rne(float f) {
    unsigned u = __float_as_uint(f);
    return (unsigned short)((u + 0x7fffu + ((u >> 16) & 1u)) >> 16);
}

// fp32 -> bf16 (rne); thread handles 8 elements (16B store)
__global__ void cvt_kernel(const float* __restrict__ x,
                           unsigned short* __restrict__ xh, int n_elem8)
{
    int i = blockIdx.x * blockDim.x + threadIdx.x;
    if (i >= n_elem8) return;
    const float4* xp = (const float4*)x;
    float4 v0 = xp[i * 2], v1 = xp[i * 2 + 1];
    float v[8] = {v0.x, v0.y, v0.z, v0.w, v1.x, v1.y, v1.z, v1.w};
    unsigned h[8];
#pragma unroll
    for (int k = 0; k < 8; ++k) h[k] = f2bf_rne(v[k]);
    uint4 ph;
    ph.x = h[0] | (h[1] << 16); ph.y = h[2] | (h[3] << 16);
    ph.z = h[4] | (h[5] << 16); ph.w = h[6] | (h[7] << 16);
    ((uint4*)xh)[i] = ph;
}

__global__ void sqnorm_kernel(const float* __restrict__ x, float* __restrict__ sqn, int n)
{
    int i = blockIdx.x * blockDim.x + threadIdx.x;
    if (i >= n) return;
    const float4* xp = (const float4*)(x + (size_t)i * D);
    float sum = 0.0f;
#pragma unroll
    for (int k = 0; k < D / 4; ++k) {
        float4 v = xp[k];
        sum += v.x * v.x + v.y * v.y + v.z * v.z + v.w * v.w;
    }
    sqn[i] = 0.5f * sum;
}

// MFMA softmin partial: per (row-block, col-chunk), online base-2 LSE over
// z2 = log2e * (wlog + (p_j - sqn_j)/eps + (x_i . y_j)/eps), dot in bf16 MFMA.
// For symmetric (x==y) calls, diagonal sub-tiles get the exact dot 2*sqn_i
// patched in (self-term dominates the LSE at small eps; bf16 error there is fatal).
__global__ __launch_bounds__(256)
void softmin_mfma(const unsigned short* __restrict__ xh,
                  const unsigned short* __restrict__ yh,
                  const float* __restrict__ p,           // [n_cols] or nullptr
                  const float* __restrict__ sqn_col,     // [n_cols]
                  const float* __restrict__ eps_list, int eps_idx, float wlog,
                  float* __restrict__ pm, float* __restrict__ ps,  // [NCHUNK][n_rows]
                  int n_rows, int n_cols, int symmetric)
{
    __shared__ __bf16 yth[128 * YLD];
    __shared__ float  cc2s[512];

    const int t    = threadIdx.x;
    const int lane = t & 63;
    const int w    = t >> 6;        // wave 0..3, owns 32 rows
    const int lx   = lane & 15;     // col-in-tile / A-row selector
    const int q    = lane >> 4;     // quad 0..3
    const int rb = blockIdx.x, chunk = blockIdx.y;
    const int cols_per_chunk = n_cols / NCHUNK;   // 512
    const int nsub = cols_per_chunk / 128;        // 4
    const int row0 = rb * BR;

    const float eps     = eps_list[eps_idx];
    const float inv_eps = 1.0f / eps;
    const float scale2  = inv_eps * LOG2E;
    const floatx2 s2v   = (floatx2){scale2, scale2};

    // stage column constants for the whole chunk (consumed after first barrier)
    for (int idx = t; idx < cols_per_chunk; idx += 256) {
        int col = chunk * cols_per_chunk + idx;
        float pv = p ? p[col] : 0.0f;
        cc2s[idx] = (wlog + (pv - sqn_col[col]) * inv_eps) * LOG2E;
    }

    // A fragments: rows r0..r0+31, loaded once, reused for every column
    bf16x8 ah[2][2];
    {
        const int r0 = row0 + w * 32;
#pragma unroll
        for (int rt = 0; rt < 2; ++rt)
#pragma unroll
            for (int ks = 0; ks < 2; ++ks) {
                size_t off = (size_t)(r0 + rt * 16 + lx) * D + ks * 32 + q * 8;
                ah[rt][ks] = *(const bf16x8*)(xh + off);
            }
    }

    // exact self-term sqnorms for diagonal blocks
    const int diag_blk = symmetric && ((row0 / cols_per_chunk) == chunk);
    float sqr[8];
    if (diag_blk) {
#pragma unroll
        for (int idx = 0; idx < 8; ++idx) {
            int row = row0 + w * 32 + (idx >> 2) * 16 + q * 4 + (idx & 3);
            sqr[idx] = sqn_col[row];
        }
    }

    float m[8], s[8];
#pragma unroll
    for (int i = 0; i < 8; ++i) { m[i] = -__builtin_inff(); s[i] = 0.0f; }

    for (int sub = 0; sub < nsub; ++sub) {
        const int col0 = chunk * cols_per_chunk + sub * 128;
        __syncthreads();   // protect LDS from previous iteration's readers (+cc2s ready)
        {
            const uint4* gh = (const uint4*)(yh + (size_t)col0 * D);  // [128 rows][8 x 16B]
#pragma unroll
            for (int i = 0; i < 4; ++i) {
                int c = t + i * 256;           // 0..1023
                int row = c >> 3, part = c & 7;
                uint4 vh = gh[c];
                *(uint4*)(&yth[row * YLD + part * 8]) = vh;
            }
        }
        __syncthreads();

        floatx4 acc[8][2];
#pragma unroll
        for (int ct = 0; ct < 8; ++ct)
#pragma unroll
            for (int rt = 0; rt < 2; ++rt) acc[ct][rt] = (floatx4){0.f, 0.f, 0.f, 0.f};

#pragma unroll
        for (int ct = 0; ct < 8; ++ct) {
            const int cl = ct * 16 + lx;
            bf16x8 bh0 = *(const bf16x8*)&yth[cl * YLD + q * 8];
            bf16x8 bh1 = *(const bf16x8*)&yth[cl * YLD + 32 + q * 8];
#pragma unroll
            for (int rt = 0; rt < 2; ++rt) {
                floatx4 a = acc[ct][rt];
                a = __builtin_amdgcn_mfma_f32_16x16x32_bf16(ah[rt][0], bh0, a, 0, 0, 0);
                a = __builtin_amdgcn_mfma_f32_16x16x32_bf16(ah[rt][1], bh1, a, 0, 0, 0);
                acc[ct][rt] = a;
            }
        }

        // exact diagonal patch (only on the one diagonal sub-tile of diagonal blocks)
        if (diag_blk && col0 == row0) {
#pragma unroll
            for (int rt = 0; rt < 2; ++rt)
#pragma unroll
                for (int r = 0; r < 4; ++r) {
                    if (lx == q * 4 + r) {
                        const float v = 2.0f * sqr[rt * 4 + r];
#pragma unroll
                        for (int ct = 0; ct < 8; ++ct)
                            if (ct == w * 2 + rt) acc[ct][rt][r] = v;
                    }
                }
        }

        // column constants as packed pairs (pair cp covers ct = 2cp, 2cp+1)
        const int subbase = sub * 128;
        floatx2 ccv[4];
#pragma unroll
        for (int cp = 0; cp < 4; ++cp)
            ccv[cp] = (floatx2){cc2s[subbase + cp * 32 + lx],
                                cc2s[subbase + cp * 32 + 16 + lx]};

        // epilogue: batched online-LSE update, packed fp32 (v_pk_*), native v_exp
        // C layout: acc[ct][rt][r] is row (rt*16 + q*4 + r), col (ct*16 + lx)
#pragma unroll
        for (int rt = 0; rt < 2; ++rt)
#pragma unroll
            for (int r = 0; r < 4; ++r) {
                const int idx = rt * 4 + r;
                floatx2 zv[4];
#pragma unroll
                for (int cp = 0; cp < 4; ++cp) {
                    floatx2 av = (floatx2){acc[cp * 2][rt][r], acc[cp * 2 + 1][rt][r]};
                    zv[cp] = __builtin_elementwise_fma(av, s2v, ccv[cp]);
                }
                floatx2 zm2 = __builtin_elementwise_max(
                    __builtin_elementwise_max(zv[0], zv[1]),
                    __builtin_elementwise_max(zv[2], zv[3]));
                const float M = fmaxf(m[idx], fmaxf(zm2.x, zm2.y));
                const floatx2 Mv = (floatx2){M, M};
                floatx2 sv = (floatx2){0.f, 0.f};
#pragma unroll
                for (int cp = 0; cp < 4; ++cp) {
                    floatx2 d = zv[cp] - Mv;
                    sv += (floatx2){exp2fast(d.x), exp2fast(d.y)};
                }
                s[idx] = fmaf(s[idx], exp2fast(m[idx] - M), sv.x + sv.y);
                m[idx] = M;
            }
    }

    // reduce (m,s) across the 16 lanes sharing the same rows
#pragma unroll
    for (int idx = 0; idx < 8; ++idx) {
        float mm = m[idx], ss = s[idx];
#pragma unroll
        for (int d = 1; d < 16; d <<= 1) {
            float mo = __shfl_xor(mm, d, 64);
            float so = __shfl_xor(ss, d, 64);
            float M = fmaxf(mm, mo);
            ss = ss * exp2fast(mm - M) + so * exp2fast(mo - M);
            mm = M;
        }
        m[idx] = mm; s[idx] = ss;
    }
    if (lx == 0) {
#pragma unroll
        for (int idx = 0; idx < 8; ++idx) {
            const int rt = idx >> 2, r = idx & 3;
            const int row = row0 + w * 32 + rt * 16 + q * 4 + r;
            pm[chunk * n_rows + row] = m[idx];
            ps[chunk * n_rows + row] = s[idx];
        }
    }
}

__global__ void softmin_merge(const float* __restrict__ pm, const float* __restrict__ ps,
                              const float* __restrict__ sqn_row,
                              const float* __restrict__ eps_list, int eps_idx,
                              const float* __restrict__ oldpot, float* __restrict__ newpot,
                              int n_rows, int mix)
{
    int i = blockIdx.x * blockDim.x + threadIdx.x;
    if (i >= n_rows) return;
    float eps = eps_list[eps_idx];
    float M = -__builtin_inff();
    for (int c = 0; c < NCHUNK; ++c) M = fmaxf(M, pm[c * n_rows + i]);
    float S = 0.0f;
    for (int c = 0; c < NCHUNK; ++c) S += ps[c * n_rows + i] * exp2fast(pm[c * n_rows + i] - M);
    float val = sqn_row[i] - eps * LN2 * (M + log2fast(S));
    newpot[i] = mix ? 0.5f * (oldpot[i] + val) : val;
}

__global__ void final_reduce(const float* __restrict__ f_ba_f, const float* __restrict__ f_aa_f,
                             const float* __restrict__ g_ab_f, const float* __restrict__ g_bb_f,
                             int n, int mcount, float* __restrict__ out)
{
    __shared__ float red[256];
    float s1 = 0.0f, s2 = 0.0f;
    for (int i = threadIdx.x; i < n; i += 256)      s1 += (f_ba_f[i] - f_aa_f[i]);
    for (int i = threadIdx.x; i < mcount; i += 256) s2 += (g_ab_f[i] - g_bb_f[i]);
    red[threadIdx.x] = s1 / (float)n + s2 / (float)mcount;
    __syncthreads();
    for (int off = 128; off > 0; off >>= 1) {
        if (threadIdx.x < off) red[threadIdx.x] += red[threadIdx.x + off];
        __syncthreads();
    }
    if (threadIdx.x == 0) out[0] = red[0];
}

extern "C" void kernel_launch(void* const* d_in, const int* in_sizes, int n_in,
                              void* d_out, int out_size, void* d_ws, size_t ws_size,
                              hipStream_t stream)
{
    const float* g        = (const float*)d_in[0];
    const float* Y        = (const float*)d_in[1];
    const float* eps_list = (const float*)d_in[2];
    const int N = in_sizes[0] / D;
    const int M = in_sizes[1] / D;
    const int L = in_sizes[2];
    const float a_log = -logf((float)N);
    const float b_log = -logf((float)M);
    const int NM = (N > M) ? N : M;

    // bf16 buffers first (16B-aligned carve)
    unsigned short* us = (unsigned short*)d_ws;
    unsigned short* gxh = us; us += (size_t)N * D;
    unsigned short* gyh = us; us += (size_t)M * D;

    float* ws = (float*)us;
    float* sqn_x = ws; ws += N;
    float* sqn_y = ws; ws += M;
    float* fa[2];  fa[0]  = ws; ws += N; fa[1]  = ws; ws += N;
    float* gb[2];  gb[0]  = ws; ws += M; gb[1]  = ws; ws += M;
    float* gab[2]; gab[0] = ws; ws += M; gab[1] = ws; ws += M;
    float* fba[2]; fba[0] = ws; ws += N; fba[1] = ws; ws += N;
    float* f_ba_f = ws; ws += N;
    float* f_aa_f = ws; ws += N;
    float* g_ab_f = ws; ws += M;
    float* g_bb_f = ws; ws += M;
    float* pm = ws; ws += (size_t)NCHUNK * NM;
    float* psb = ws; ws += (size_t)NCHUNK * NM;

    sqnorm_kernel<<<(N + 255) / 256, 256, 0, stream>>>(g, sqn_x, N);
    sqnorm_kernel<<<(M + 255) / 256, 256, 0, stream>>>(Y, sqn_y, M);
    cvt_kernel<<<(N * D / 8 + 255) / 256, 256, 0, stream>>>(g, gxh, N * D / 8);
    cvt_kernel<<<(M * D / 8 + 255) / 256, 256, 0, stream>>>(Y, gyh, M * D / 8);

    auto softmin = [&](const unsigned short* rxh, const unsigned short* cyh,
                       const float* p, const float* sqn_c, const float* sqn_r,
                       int eidx, float wl, const float* oldp, float* newp,
                       int nr, int nc, int mix, int sym) {
        dim3 grid(nr / BR, NCHUNK);
        softmin_mfma<<<grid, 256, 0, stream>>>(rxh, cyh, p, sqn_c, eps_list,
                                               eidx, wl, pm, psb, nr, nc, sym);
        softmin_merge<<<(nr + 255) / 256, 256, 0, stream>>>(pm, psb, sqn_r, eps_list, eidx,
                                                            oldp, newp, nr, mix);
    };

    int cur = 0;
    // initialization at eps_list[0], h = wlog only
    softmin(gxh, gxh, nullptr, sqn_x, sqn_x, 0, a_log, nullptr, fa[cur],  N, N, 0, 1);
    softmin(gyh, gyh, nullptr, sqn_y, sqn_y, 0, b_log, nullptr, gb[cur],  M, M, 0, 1);
    softmin(gyh, gxh, nullptr, sqn_x, sqn_y, 0, a_log, nullptr, gab[cur], M, N, 0, 0);
    softmin(gxh, gyh, nullptr, sqn_y, sqn_x, 0, b_log, nullptr, fba[cur], N, M, 0, 0);

    // scan over the eps schedule; symmetrized averaged updates
    for (int k = 0; k < L; ++k) {
        int nxt = cur ^ 1;
        softmin(gxh, gyh, gab[cur], sqn_y, sqn_x, k, b_log, fba[cur], fba[nxt], N, M, 1, 0);
        softmin(gyh, gxh, fba[cur], sqn_x, sqn_y, k, a_log, gab[cur], gab[nxt], M, N, 1, 0);
        softmin(gxh, gxh, fa[cur],  sqn_x, sqn_x, k, a_log, fa[cur],  fa[nxt],  N, N, 1, 1);
        softmin(gyh, gyh, gb[cur],  sqn_y, sqn_y, k, b_log, gb[cur],  gb[nxt],  M, M, 1, 1);
        cur = nxt;
    }

    // final extrapolation at eps_list[L-1] (no averaging)
    softmin(gxh, gyh, gab[cur], sqn_y, sqn_x, L - 1, b_log, nullptr, f_ba_f, N, M, 0, 0);
    softmin(gyh, gxh, fba[cur], sqn_x, sqn_y, L - 1, a_log, nullptr, g_ab_f, M, N, 0, 0);
    softmin(gxh, gxh, fa[cur],  sqn_x, sqn_x, L - 1, a_log, nullptr, f_aa_f, N, N, 0, 1);
    softmin(gyh, gyh, gb[cur],  sqn_y, sqn_y, L - 1, b_log, nullptr, g_bb_f, M, M, 0, 1);

    final_reduce<<<1, 256, 0, stream>>>(f_ba_f, f_aa_f, g_ab_f, g_bb_f, N, M, (float*)d_out);
}